// Round 1
// baseline (20951.035 us; speedup 1.0000x reference)
//
#include <hip/hip_runtime.h>
#include <math.h>

typedef _Float16 f16;
typedef _Float16 f16x8 __attribute__((ext_vector_type(8)));
typedef float f32x4 __attribute__((ext_vector_type(4)));

#define NBATCH 256
#define NS     512
#define NH     256
#define NG     1024
#define NV     90

__device__ __forceinline__ float sgf(float x) {
    // sigmoid(x) = 1/(1+2^(-x*log2 e))
    return __builtin_amdgcn_rcpf(1.f + exp2f(-1.44269504089f * x));
}
__device__ __forceinline__ float thf(float x) {
    // tanh(x) = 2/(1+2^(-2x*log2 e)) - 1
    return 2.f * __builtin_amdgcn_rcpf(1.f + exp2f(-2.88539008178f * x)) - 1.f;
}

// ---------------- setup kernels ----------------

// T0[v][n] = sum_e emb[v][e]*Wih0[n][e] + bih0[n] + bhh0[n]
__global__ void build_t0(const float* __restrict__ emb, const float* __restrict__ wih0,
                         const float* __restrict__ bih0, const float* __restrict__ bhh0,
                         float* __restrict__ T0) {
    int v = blockIdx.x;
    __shared__ float e[8];
    if (threadIdx.x < 8) e[threadIdx.x] = emb[v * 8 + threadIdx.x];
    __syncthreads();
    for (int n = threadIdx.x; n < NG; n += blockDim.x) {
        float s = bih0[n] + bhh0[n];
        #pragma unroll
        for (int k = 0; k < 8; ++k) s += wih0[n * 8 + k] * e[k];
        T0[v * NG + n] = s;
    }
}

// B-fragment pack: value = W[n][k], n = w*128 + nt*16 + (l&15), k = kt*32 + (l>>4)*8 + e
__global__ void pack_whh0(const float* __restrict__ whh0, f16* __restrict__ wp) {
    int gid = blockIdx.x * blockDim.x + threadIdx.x;  // 32768
    int l = gid & 63, kt = (gid >> 6) & 7, nt = (gid >> 9) & 7, w = gid >> 12;
    int n = w * 128 + nt * 16 + (l & 15);
    int k = kt * 32 + (l >> 4) * 8;
    f16x8 v;
    #pragma unroll
    for (int e = 0; e < 8; ++e) v[e] = (f16)whh0[n * 256 + k + e];
    *(f16x8*)(wp + (size_t)gid * 8) = v;
}

// concat K: k<256 -> Wih1, k>=256 -> Whh1
__global__ void pack_w1(const float* __restrict__ wih1, const float* __restrict__ whh1,
                        f16* __restrict__ wp) {
    int gid = blockIdx.x * blockDim.x + threadIdx.x;  // 65536
    int l = gid & 63, kt = (gid >> 6) & 15, nt = (gid >> 10) & 7, w = gid >> 13;
    int n = w * 128 + nt * 16 + (l & 15);
    int k = kt * 32 + (l >> 4) * 8;
    const float* src = (k < 256) ? (wih1 + n * 256 + k) : (whh1 + n * 256 + (k - 256));
    f16x8 v;
    #pragma unroll
    for (int e = 0; e < 8; ++e) v[e] = (f16)src[e];
    *(f16x8*)(wp + (size_t)gid * 8) = v;
}

__global__ void pack_wfc(const float* __restrict__ wfc, f16* __restrict__ wp) {
    int gid = blockIdx.x * blockDim.x + threadIdx.x;  // 3072
    int l = gid & 63, kt = (gid >> 6) & 7, nt = gid >> 9;  // nt 0..5
    int n = nt * 16 + (l & 15);
    int k = kt * 32 + (l >> 4) * 8;
    f16x8 v;
    #pragma unroll
    for (int e = 0; e < 8; ++e) v[e] = (n < NV) ? (f16)wfc[n * 256 + k + e] : (f16)0.f;
    *(f16x8*)(wp + (size_t)gid * 8) = v;
}

// ---------------- layer 0 recurrence ----------------
// 16 wgs x 512 thr (8 waves). Wave w owns gate slice n in [128w,128w+128).
// LDS: gbuf 64KB gates f32 (swz: elem = m*1024 + (n^m)); hbuf 8KB h f16
// (swz: elem = b*256 + (k ^ (8*(b&7)))).
__launch_bounds__(512)
__global__ void stage_a(const int* __restrict__ x, const float* __restrict__ T0,
                        const f16* __restrict__ Wp, f16* __restrict__ h1p) {
    extern __shared__ char smem[];
    float* gbuf = (float*)smem;
    f16*   hbuf = (f16*)(smem + 65536);
    const int tid = threadIdx.x;
    const int w = tid >> 6, l = tid & 63;
    const int l15 = l & 15, lq = l >> 4;
    const int bt = blockIdx.x;

    for (int i = tid; i < 16 * 256; i += 512) hbuf[i] = (f16)0.f;
    __syncthreads();

    float c[8];
    #pragma unroll
    for (int r = 0; r < 8; ++r) c[r] = 0.f;

    const int hswz = 8 * (l15 & 7);
    const f16* wbase = Wp + (size_t)w * 8 * 8 * 512 + l * 8;
    const int jbase = w * 32 + lq * 8;

    for (int t = 0; t < NS; ++t) {
        // A-fragments of h(t-1): lane holds h[b=l15][k = kt*32 + lq*8 + e]
        f16x8 a[8];
        #pragma unroll
        for (int kt = 0; kt < 8; ++kt)
            a[kt] = *(const f16x8*)&hbuf[l15 * 256 + ((kt * 32 + lq * 8) ^ hswz)];

        // store h1(t-1) fragments (wave w stores kt=w) for stage_c
        if (t > 0) {
            f16x8 hv = *(const f16x8*)&hbuf[l15 * 256 + ((w * 32 + lq * 8) ^ hswz)];
            *(f16x8*)&h1p[((((size_t)bt * NS + (t - 1)) * 8 + w) * 64 + l) * 8] = hv;
        }

        // acc init from token gate table (C/D row m = lq*4+r, col n)
        f32x4 acc[8];
        #pragma unroll
        for (int r = 0; r < 4; ++r) {
            int xv = x[(bt * 16 + lq * 4 + r) * NS + t];
            const float* t0r = T0 + (size_t)xv * NG + w * 128 + l15;
            #pragma unroll
            for (int nt = 0; nt < 8; ++nt) acc[nt][r] = t0r[nt * 16];
        }
        #pragma unroll
        for (int nt = 0; nt < 8; ++nt) {
            #pragma unroll
            for (int kt = 0; kt < 8; ++kt) {
                f16x8 bf = *(const f16x8*)&wbase[(size_t)(nt * 8 + kt) * 512];
                acc[nt] = __builtin_amdgcn_mfma_f32_16x16x32_f16(a[kt], bf, acc[nt], 0, 0, 0);
            }
        }
        // scatter gates to LDS
        #pragma unroll
        for (int nt = 0; nt < 8; ++nt) {
            int n = w * 128 + nt * 16 + l15;
            #pragma unroll
            for (int r = 0; r < 4; ++r) {
                int m = lq * 4 + r;
                gbuf[m * 1024 + (n ^ m)] = acc[nt][r];
            }
        }
        __syncthreads();
        // elementwise: lane owns b=l15, j = jbase..jbase+7
        {
            const int b = l15;
            #pragma unroll
            for (int r = 0; r < 8; ++r) {
                int j = jbase + r;
                int e0 = b * 1024 + (j ^ b);
                float gi = gbuf[e0];
                float gf = gbuf[e0 + 256];
                float gg = gbuf[e0 + 512];
                float go = gbuf[e0 + 768];
                float iv = sgf(gi), fv = sgf(gf), gv = thf(gg), ov = sgf(go);
                c[r] = fv * c[r] + iv * gv;
                float h = ov * thf(c[r]);
                hbuf[b * 256 + (j ^ hswz)] = (f16)h;
            }
        }
        __syncthreads();
    }
    // final h1 store (t = NS-1)
    {
        f16x8 hv = *(const f16x8*)&hbuf[l15 * 256 + ((w * 32 + lq * 8) ^ hswz)];
        *(f16x8*)&h1p[((((size_t)bt * NS + (NS - 1)) * 8 + w) * 64 + l) * 8] = hv;
    }
}

// ---------------- layer 1 recurrence + fused FC ----------------
__launch_bounds__(512)
__global__ void stage_c(const f16* __restrict__ h1p, const f16* __restrict__ W1p,
                        const float* __restrict__ bih1, const float* __restrict__ bhh1,
                        const f16* __restrict__ Wfcp, const float* __restrict__ bfc,
                        float* __restrict__ out) {
    extern __shared__ char smem[];
    float* gbuf = (float*)smem;
    f16*   hbuf = (f16*)(smem + 65536);
    const int tid = threadIdx.x;
    const int w = tid >> 6, l = tid & 63;
    const int l15 = l & 15, lq = l >> 4;
    const int bt = blockIdx.x;

    for (int i = tid; i < 16 * 256; i += 512) hbuf[i] = (f16)0.f;
    __syncthreads();

    float c[8];
    #pragma unroll
    for (int r = 0; r < 8; ++r) c[r] = 0.f;

    float bias[8];
    #pragma unroll
    for (int nt = 0; nt < 8; ++nt) {
        int n = w * 128 + nt * 16 + l15;
        bias[nt] = bih1[n] + bhh1[n];
    }
    const int nfc = w * 16 + l15;
    const float bfcv = (w < 6 && nfc < NV) ? bfc[nfc] : 0.f;

    const int hswz = 8 * (l15 & 7);
    const f16* wbase  = W1p + (size_t)w * 8 * 16 * 512 + l * 8;
    const f16* fcbase = Wfcp + (size_t)w * 8 * 512 + l * 8;  // dereferenced only if w<6
    const f16* h1t = h1p + (size_t)bt * NS * 4096 + l * 8;
    const int jbase = w * 32 + lq * 8;

    for (int t = 0; t < NS; ++t) {
        f16x8 a1[8], a2[8];
        #pragma unroll
        for (int kt = 0; kt < 8; ++kt)
            a1[kt] = *(const f16x8*)&h1t[(size_t)t * 4096 + kt * 512];
        #pragma unroll
        for (int kt = 0; kt < 8; ++kt)
            a2[kt] = *(const f16x8*)&hbuf[l15 * 256 + ((kt * 32 + lq * 8) ^ hswz)];

        // fused FC for t-1 (waves 0..5), uses h2(t-1) = a2
        if (t > 0 && w < 6) {
            f32x4 facc = {bfcv, bfcv, bfcv, bfcv};
            #pragma unroll
            for (int kt = 0; kt < 8; ++kt) {
                f16x8 bf = *(const f16x8*)&fcbase[(size_t)kt * 512];
                facc = __builtin_amdgcn_mfma_f32_16x16x32_f16(a2[kt], bf, facc, 0, 0, 0);
            }
            if (nfc < NV) {
                #pragma unroll
                for (int r = 0; r < 4; ++r)
                    out[((size_t)(bt * 16 + lq * 4 + r) * NS + (t - 1)) * NV + nfc] = facc[r];
            }
        }

        f32x4 acc[8];
        #pragma unroll
        for (int nt = 0; nt < 8; ++nt) {
            f32x4 in4 = {bias[nt], bias[nt], bias[nt], bias[nt]};
            acc[nt] = in4;
        }
        #pragma unroll
        for (int nt = 0; nt < 8; ++nt) {
            #pragma unroll
            for (int kt = 0; kt < 8; ++kt) {
                f16x8 b1 = *(const f16x8*)&wbase[(size_t)(nt * 16 + kt) * 512];
                acc[nt] = __builtin_amdgcn_mfma_f32_16x16x32_f16(a1[kt], b1, acc[nt], 0, 0, 0);
            }
            #pragma unroll
            for (int kt = 0; kt < 8; ++kt) {
                f16x8 b2 = *(const f16x8*)&wbase[(size_t)(nt * 16 + 8 + kt) * 512];
                acc[nt] = __builtin_amdgcn_mfma_f32_16x16x32_f16(a2[kt], b2, acc[nt], 0, 0, 0);
            }
        }
        #pragma unroll
        for (int nt = 0; nt < 8; ++nt) {
            int n = w * 128 + nt * 16 + l15;
            #pragma unroll
            for (int r = 0; r < 4; ++r) {
                int m = lq * 4 + r;
                gbuf[m * 1024 + (n ^ m)] = acc[nt][r];
            }
        }
        __syncthreads();
        {
            const int b = l15;
            #pragma unroll
            for (int r = 0; r < 8; ++r) {
                int j = jbase + r;
                int e0 = b * 1024 + (j ^ b);
                float gi = gbuf[e0];
                float gf = gbuf[e0 + 256];
                float gg = gbuf[e0 + 512];
                float go = gbuf[e0 + 768];
                float iv = sgf(gi), fv = sgf(gf), gv = thf(gg), ov = sgf(go);
                c[r] = fv * c[r] + iv * gv;
                float h = ov * thf(c[r]);
                hbuf[b * 256 + (j ^ hswz)] = (f16)h;
            }
        }
        __syncthreads();
    }
    // final FC for t = NS-1
    if (w < 6) {
        f16x8 a2[8];
        #pragma unroll
        for (int kt = 0; kt < 8; ++kt)
            a2[kt] = *(const f16x8*)&hbuf[l15 * 256 + ((kt * 32 + lq * 8) ^ hswz)];
        f32x4 facc = {bfcv, bfcv, bfcv, bfcv};
        #pragma unroll
        for (int kt = 0; kt < 8; ++kt) {
            f16x8 bf = *(const f16x8*)&fcbase[(size_t)kt * 512];
            facc = __builtin_amdgcn_mfma_f32_16x16x32_f16(a2[kt], bf, facc, 0, 0, 0);
        }
        if (nfc < NV) {
            #pragma unroll
            for (int r = 0; r < 4; ++r)
                out[((size_t)(bt * 16 + lq * 4 + r) * NS + (NS - 1)) * NV + nfc] = facc[r];
        }
    }
}

extern "C" void kernel_launch(void* const* d_in, const int* in_sizes, int n_in,
                              void* d_out, int out_size, void* d_ws, size_t ws_size,
                              hipStream_t stream) {
    const int*   x    = (const int*)  d_in[0];
    const float* emb  = (const float*)d_in[1];
    const float* wih0 = (const float*)d_in[2];
    const float* whh0 = (const float*)d_in[3];
    const float* bih0 = (const float*)d_in[4];
    const float* bhh0 = (const float*)d_in[5];
    const float* wih1 = (const float*)d_in[6];
    const float* whh1 = (const float*)d_in[7];
    const float* bih1 = (const float*)d_in[8];
    const float* bhh1 = (const float*)d_in[9];
    const float* wfc  = (const float*)d_in[10];
    const float* bfc  = (const float*)d_in[11];
    float* out = (float*)d_out;

    char* ws = (char*)d_ws;
    float* T0   = (float*)(ws);                                   // 368640 B
    f16*   w0p  = (f16*)(ws + 368640);                            // 524288 B
    f16*   w1p  = (f16*)(ws + 368640 + 524288);                   // 1048576 B
    f16*   wfcp = (f16*)(ws + 368640 + 524288 + 1048576);         // 49152 B
    f16*   h1p  = (f16*)(ws + 368640 + 524288 + 1048576 + 49152); // 64 MB

    hipFuncSetAttribute(reinterpret_cast<const void*>(stage_a),
                        hipFuncAttributeMaxDynamicSharedMemorySize, 73728);
    hipFuncSetAttribute(reinterpret_cast<const void*>(stage_c),
                        hipFuncAttributeMaxDynamicSharedMemorySize, 73728);

    build_t0<<<90, 256, 0, stream>>>(emb, wih0, bih0, bhh0, T0);
    pack_whh0<<<128, 256, 0, stream>>>(whh0, w0p);
    pack_w1<<<256, 256, 0, stream>>>(wih1, whh1, w1p);
    pack_wfc<<<12, 256, 0, stream>>>(wfc, wfcp);
    stage_a<<<16, 512, 73728, stream>>>(x, T0, w0p, h1p);
    stage_c<<<16, 512, 73728, stream>>>(h1p, w1p, bih1, bhh1, wfcp, bfc, out);
}

// Round 3
// 6445.763 us; speedup vs baseline: 3.2504x; 3.2504x over previous
//
#include <hip/hip_runtime.h>
#include <math.h>

typedef _Float16 f16;
typedef _Float16 f16x8 __attribute__((ext_vector_type(8)));
typedef _Float16 f16x4 __attribute__((ext_vector_type(4)));
typedef float f32x4 __attribute__((ext_vector_type(4)));

#define NS     512
#define NG     1024
#define NV     90

// LDS map for rnn_chunk (bytes):
//   [0, 16384)      : h double buffer, 2 x 16 rows x 256 f16 (XOR-swizzled, 32-granule)
//   [16384, 159744) : per-wave LDS-resident weight frags: wave w at 16384 + w*35840
#define R_LDS_BYTES 159744

__device__ __forceinline__ float sgf(float x) {
    return __builtin_amdgcn_rcpf(1.f + exp2f(-1.44269504089f * x));
}
__device__ __forceinline__ float thf(float x) {
    return 2.f * __builtin_amdgcn_rcpf(1.f + exp2f(-2.88539008178f * x)) - 1.f;
}

// frag id f = (jt*4+g)*8 + kt. 93 frags in regs, 35 in LDS.
__device__ __forceinline__ bool in_lds_f(int f) {
    return ((f & 7) >= 6) || (f >= 123);
}
__device__ __forceinline__ int reg_idx_f(int f) {
    return (f >> 3) * 6 + (f & 7);
}
__device__ __forceinline__ int lds_idx_f(int f) {
    int kt = f & 7;
    return (kt >= 6) ? ((f >> 3) * 2 + (kt - 6)) : (32 + (kt - 3));
}

// ---------------- setup kernels ----------------

// T0p[v][w][jt][l15][g] f16 = sum_e emb[v][e]*Wih0[n][e] + bih0[n]+bhh0[n],
// n = g*256 + w*64 + jt*16 + l15
__global__ void build_t0p(const float* __restrict__ emb, const float* __restrict__ wih0,
                          const float* __restrict__ bih0, const float* __restrict__ bhh0,
                          f16* __restrict__ t0p) {
    int v = blockIdx.x, tid = threadIdx.x;
    int w = tid >> 6, jt = (tid >> 4) & 3, l15 = tid & 15;
    __shared__ float e[8];
    if (tid < 8) e[tid] = emb[v * 8 + tid];
    __syncthreads();
    f16x4 o;
    #pragma unroll
    for (int g = 0; g < 4; ++g) {
        int n = g * 256 + w * 64 + jt * 16 + l15;
        float s = bih0[n] + bhh0[n];
        #pragma unroll
        for (int k = 0; k < 8; ++k) s += e[k] * wih0[n * 8 + k];
        o[g] = (f16)s;
    }
    *(f16x4*)&t0p[((((size_t)v * 4 + w) * 4 + jt) * 16 + l15) * 4] = o;
}

// pack 1024x256 f32 weight into B-frag layout Wp[(w*128+f)*64+l][8]
__global__ void pack_rw(const float* __restrict__ W, f16* __restrict__ Wp) {
    int gid = blockIdx.x * 256 + threadIdx.x;   // 32768
    int l = gid & 63, f = (gid >> 6) & 127, w = gid >> 13;
    int kt = f & 7, g = (f >> 3) & 3, jt = f >> 5;
    int n = g * 256 + w * 64 + jt * 16 + (l & 15);
    int k = kt * 32 + (l >> 4) * 8;
    f16x8 v;
    #pragma unroll
    for (int e = 0; e < 8; ++e) v[e] = (f16)W[n * 256 + k + e];
    *(f16x8*)&Wp[(size_t)gid * 8] = v;
}

// pack Wfc (90x256) zero-padded to 96 rows: Wfcp[(nt*8+kt)*64+l][8]
__global__ void pack_fc(const float* __restrict__ Wfc, f16* __restrict__ Wp) {
    int gid = blockIdx.x * 256 + threadIdx.x;   // 3072
    int l = gid & 63, kt = (gid >> 6) & 7, nt = gid >> 9;
    int n = nt * 16 + (l & 15);
    int k = kt * 32 + (l >> 4) * 8;
    f16x8 v;
    #pragma unroll
    for (int e = 0; e < 8; ++e) v[e] = (n < NV) ? (f16)Wfc[n * 256 + k + e] : (f16)0.f;
    *(f16x8*)&Wp[(size_t)gid * 8] = v;
}

// ---------------- recurrent chunk kernel (both layers) ----------------
// grid 16 (batch groups of 16 rows), block 256 (4 waves, 1/SIMD).
// Wave w owns hidden slice j in [w*64, w*64+64) -> gate rows {g*256+j}.
// Runs steps t0..t0+tc-1; state (c,h) persists in cst/hst between chunks.
// Dumps h(t) for each local step s to hdump[s*16+bg] as raw swizzled 8KB blob.
template<int LAYER>
__launch_bounds__(256, 1)
__global__ void rnn_chunk(const f16* __restrict__ Wp, const int* __restrict__ x,
                          const f16* __restrict__ T0p, const f16* __restrict__ xgc,
                          f16* __restrict__ hdump, float* __restrict__ cst,
                          f16* __restrict__ hst, int t0, int tc) {
    extern __shared__ char smem[];
    f16* hb = (f16*)smem;   // 2 x 4096 f16
    const int tid = threadIdx.x;
    const int w = tid >> 6, l = tid & 63, l15 = l & 15, lq = l >> 4;
    const int bg = blockIdx.x;

    const f16* wgl = Wp + ((size_t)w * 128) * 512 + l * 8;   // frag f at +f*512 (f16)
    f16* wlds = (f16*)(smem + 16384 + w * 35840);

    // stage LDS-resident frags
    #pragma unroll
    for (int fi = 0; fi < 35; ++fi) {
        int f = (fi < 32) ? ((fi >> 1) * 8 + 6 + (fi & 1)) : (123 + (fi - 32));
        *(f16x8*)&wlds[fi * 512 + l * 8] = *(const f16x8*)&wgl[(size_t)f * 512];
    }
    // preload register frags
    f16x8 w_r[93];
    #pragma unroll
    for (int f = 0; f < 128; ++f)
        if (!in_lds_f(f))
            w_r[reg_idx_f(f)] = *(const f16x8*)&wgl[(size_t)f * 512];

    float c[16];
    if (t0 == 0) {
        #pragma unroll
        for (int i = 0; i < 16; ++i) hb[i * 256 + tid] = (f16)0.f;
        #pragma unroll
        for (int i = 0; i < 16; ++i) c[i] = 0.f;
    } else {
        // restore h state into buffer 0 (raw 8KB blob) and c state
        const char* hsrc = (const char*)hst + (size_t)bg * 8192 + tid * 32;
        *(uint4*)(smem + tid * 32)      = *(const uint4*)hsrc;
        *(uint4*)(smem + tid * 32 + 16) = *(const uint4*)(hsrc + 16);
        const float* cp = cst + (((size_t)bg * 4 + w) * 64 + l) * 16;
        #pragma unroll
        for (int i = 0; i < 16; ++i) c[i] = cp[i];
    }
    __syncthreads();

    const int hswz = 32 * (l15 & 7);

    for (int s = 0; s < tc; ++s) {
        const int t = t0 + s;
        const int rb = (s & 1) * 4096, wb = rb ^ 4096;

        // dump h(t-1) (raw swizzled blob) - fire and forget
        if (s > 0) {
            const char* src = smem + rb * 2 + tid * 32;
            uint4 d0 = *(const uint4*)src;
            uint4 d1 = *(const uint4*)(src + 16);
            f16* dst = hdump + (((size_t)(s - 1) * 16 + bg) << 12) + tid * 16;
            *(uint4*)dst = d0;
            *((uint4*)dst + 1) = d1;
        }

        int xv[4];
        if constexpr (LAYER == 0) {
            #pragma unroll
            for (int r = 0; r < 4; ++r)
                xv[r] = x[(bg * 16 + lq * 4 + r) * NS + t];
        }

        uint4 ivq[2][2];
        f16x4 iv0[2][4];
        // preload chunk 0's input-gate contribution
        if constexpr (LAYER == 0) {
            #pragma unroll
            for (int r = 0; r < 4; ++r)
                iv0[0][r] = *(const f16x4*)&T0p[((((size_t)xv[r] * 4 + w) * 4 + 0) * 16 + l15) * 4];
        } else {
            const f16* p_ = xgc + (((size_t)(s * 16 + bg) * 16) + w * 4 + 0) * 1024 + l * 16;
            ivq[0][0] = *(const uint4*)p_;
            ivq[0][1] = *(const uint4*)(p_ + 8);
        }

        #pragma unroll
        for (int jt = 0; jt < 4; ++jt) {
            const int cs = jt & 1, nx = cs ^ 1;
            if (jt < 3) {   // prefetch next chunk's contribution
                if constexpr (LAYER == 0) {
                    #pragma unroll
                    for (int r = 0; r < 4; ++r)
                        iv0[nx][r] = *(const f16x4*)&T0p[((((size_t)xv[r] * 4 + w) * 4 + (jt + 1)) * 16 + l15) * 4];
                } else {
                    const f16* p_ = xgc + (((size_t)(s * 16 + bg) * 16) + w * 4 + (jt + 1)) * 1024 + l * 16;
                    ivq[nx][0] = *(const uint4*)p_;
                    ivq[nx][1] = *(const uint4*)(p_ + 8);
                }
            }

            f32x4 acc[4];
            #pragma unroll
            for (int g = 0; g < 4; ++g) acc[g] = (f32x4){0.f, 0.f, 0.f, 0.f};

            #pragma unroll
            for (int kt = 0; kt < 8; ++kt) {
                f16x8 a = *(const f16x8*)&hb[rb + l15 * 256 + ((kt * 32 + lq * 8) ^ hswz)];
                #pragma unroll
                for (int g = 0; g < 4; ++g) {
                    const int f = (jt * 4 + g) * 8 + kt;
                    f16x8 bfr;
                    if (in_lds_f(f)) bfr = *(const f16x8*)&wlds[lds_idx_f(f) * 512 + l * 8];
                    else             bfr = w_r[reg_idx_f(f)];
                    acc[g] = __builtin_amdgcn_mfma_f32_16x16x32_f16(a, bfr, acc[g], 0, 0, 0);
                }
            }

            const f16* ivf = (const f16*)&ivq[cs][0];
            #pragma unroll
            for (int r = 0; r < 4; ++r) {
                float gi, gf, gg, go;
                if constexpr (LAYER == 0) {
                    gi = acc[0][r] + (float)iv0[cs][r][0];
                    gf = acc[1][r] + (float)iv0[cs][r][1];
                    gg = acc[2][r] + (float)iv0[cs][r][2];
                    go = acc[3][r] + (float)iv0[cs][r][3];
                } else {
                    gi = acc[0][r] + (float)ivf[0 * 4 + r];
                    gf = acc[1][r] + (float)ivf[1 * 4 + r];
                    gg = acc[2][r] + (float)ivf[2 * 4 + r];
                    go = acc[3][r] + (float)ivf[3 * 4 + r];
                }
                float si = sgf(gi), sf = sgf(gf), tg = thf(gg), so = sgf(go);
                const int ci = jt * 4 + r;
                c[ci] = sf * c[ci] + si * tg;
                float h = so * thf(c[ci]);
                const int b = lq * 4 + r;
                hb[wb + b * 256 + ((w * 64 + jt * 16 + l15) ^ (32 * (b & 7)))] = (f16)h;
            }
        }
        __syncthreads();
    }
    // epilogue: final h lives in buffer 0 (tc even). dump it + save state.
    {
        const char* src = smem + tid * 32;
        uint4 d0 = *(const uint4*)src;
        uint4 d1 = *(const uint4*)(src + 16);
        f16* dst = hdump + (((size_t)(tc - 1) * 16 + bg) << 12) + tid * 16;
        *(uint4*)dst = d0;
        *((uint4*)dst + 1) = d1;
        char* hdst = (char*)hst + (size_t)bg * 8192 + tid * 32;
        *(uint4*)hdst = d0;
        *(uint4*)(hdst + 16) = d1;
        float* cp = cst + (((size_t)bg * 4 + w) * 64 + l) * 16;
        #pragma unroll
        for (int i = 0; i < 16; ++i) cp[i] = c[i];
    }
}

// ---------------- xg1 = Wih1 @ h1 + (bih1+bhh1), frag-layout output (chunk) -----
// grid: 16(bg) x 4(ns) x (tc/16). block 256: wave wv owns jt=wv.
__launch_bounds__(256, 1)
__global__ void xg1_gemm(const f16* __restrict__ h1c, const f16* __restrict__ Wxp,
                         const float* __restrict__ bih1, const float* __restrict__ bhh1,
                         f16* __restrict__ xgc) {
    const int tid = threadIdx.x, wv = tid >> 6, l = tid & 63, l15 = l & 15, lq = l >> 4;
    const int bid = blockIdx.x, bg = bid & 15, ns = (bid >> 4) & 3, tcc = bid >> 6;

    f16x8 bf[4][8];
    #pragma unroll
    for (int g = 0; g < 4; ++g)
        #pragma unroll
        for (int kt = 0; kt < 8; ++kt)
            bf[g][kt] = *(const f16x8*)&Wxp[((size_t)(ns * 128 + (wv * 4 + g) * 8 + kt) * 64 + l) * 8];
    float bs[4];
    #pragma unroll
    for (int g = 0; g < 4; ++g) {
        int n = g * 256 + ns * 64 + wv * 16 + l15;
        bs[g] = bih1[n] + bhh1[n];
    }
    const int hswz = 32 * (l15 & 7);

    for (int tt = 0; tt < 16; ++tt) {
        int s = tcc * 16 + tt;
        const f16* blob = h1c + ((size_t)(s * 16 + bg) << 12);
        f16x8 a[8];
        #pragma unroll
        for (int kt = 0; kt < 8; ++kt)
            a[kt] = *(const f16x8*)&blob[l15 * 256 + ((kt * 32 + lq * 8) ^ hswz)];
        f32x4 acc[4];
        #pragma unroll
        for (int g = 0; g < 4; ++g) acc[g] = (f32x4){bs[g], bs[g], bs[g], bs[g]};
        #pragma unroll
        for (int kt = 0; kt < 8; ++kt)
            #pragma unroll
            for (int g = 0; g < 4; ++g)
                acc[g] = __builtin_amdgcn_mfma_f32_16x16x32_f16(a[kt], bf[g][kt], acc[g], 0, 0, 0);
        f16 ov[16];
        #pragma unroll
        for (int g = 0; g < 4; ++g)
            #pragma unroll
            for (int r = 0; r < 4; ++r) ov[g * 4 + r] = (f16)acc[g][r];
        f16* dst = xgc + (((size_t)(s * 16 + bg) * 16) + ns * 4 + wv) * 1024 + l * 16;
        *(uint4*)dst = *(uint4*)&ov[0];
        *((uint4*)dst + 1) = *(uint4*)&ov[8];
    }
}

// ---------------- final projection (chunk) ----------------
// grid: 16(bg) x (tc/4). block 4 waves; wave wv handles local step s = tb*4+wv.
__launch_bounds__(256, 1)
__global__ void fc_out(const f16* __restrict__ h2c, const f16* __restrict__ Wfcp,
                       const float* __restrict__ bfc, float* __restrict__ out, int t0) {
    const int tid = threadIdx.x, wv = tid >> 6, l = tid & 63, l15 = l & 15, lq = l >> 4;
    const int bid = blockIdx.x, bg = bid & 15, tb = bid >> 4;
    const int s = tb * 4 + wv;

    f16x8 bf[6][8];
    #pragma unroll
    for (int nt = 0; nt < 6; ++nt)
        #pragma unroll
        for (int kt = 0; kt < 8; ++kt)
            bf[nt][kt] = *(const f16x8*)&Wfcp[((size_t)(nt * 8 + kt) * 64 + l) * 8];
    float bb[6];
    #pragma unroll
    for (int nt = 0; nt < 6; ++nt) {
        int n = nt * 16 + l15;
        bb[nt] = (n < NV) ? bfc[n] : 0.f;
    }
    const int hswz = 32 * (l15 & 7);

    const f16* blob = h2c + ((size_t)(s * 16 + bg) << 12);
    f16x8 a[8];
    #pragma unroll
    for (int kt = 0; kt < 8; ++kt)
        a[kt] = *(const f16x8*)&blob[l15 * 256 + ((kt * 32 + lq * 8) ^ hswz)];
    f32x4 acc[6];
    #pragma unroll
    for (int nt = 0; nt < 6; ++nt) acc[nt] = (f32x4){bb[nt], bb[nt], bb[nt], bb[nt]};
    #pragma unroll
    for (int kt = 0; kt < 8; ++kt)
        #pragma unroll
        for (int nt = 0; nt < 6; ++nt)
            acc[nt] = __builtin_amdgcn_mfma_f32_16x16x32_f16(a[kt], bf[nt][kt], acc[nt], 0, 0, 0);
    #pragma unroll
    for (int nt = 0; nt < 6; ++nt) {
        int n = nt * 16 + l15;
        if (n < NV) {
            #pragma unroll
            for (int r = 0; r < 4; ++r)
                out[((size_t)(bg * 16 + lq * 4 + r) * NS + (t0 + s)) * NV + n] = acc[nt][r];
        }
    }
}

extern "C" void kernel_launch(void* const* d_in, const int* in_sizes, int n_in,
                              void* d_out, int out_size, void* d_ws, size_t ws_size,
                              hipStream_t stream) {
    const int*   x    = (const int*)  d_in[0];
    const float* emb  = (const float*)d_in[1];
    const float* wih0 = (const float*)d_in[2];
    const float* whh0 = (const float*)d_in[3];
    const float* bih0 = (const float*)d_in[4];
    const float* bhh0 = (const float*)d_in[5];
    const float* wih1 = (const float*)d_in[6];
    const float* whh1 = (const float*)d_in[7];
    const float* bih1 = (const float*)d_in[8];
    const float* bhh1 = (const float*)d_in[9];
    const float* wfc  = (const float*)d_in[10];
    const float* bfc  = (const float*)d_in[11];
    float* out = (float*)d_out;

    char* ws = (char*)d_ws;
    // fixed region (bytes)
    f16*   Wp0  = (f16*)(ws + 0);             //  524288
    f16*   Wp1  = (f16*)(ws + 524288);        //  524288
    f16*   Wxp  = (f16*)(ws + 1048576);       //  524288
    f16*   Wfcp = (f16*)(ws + 1572864);       //   49152
    f16*   T0p  = (f16*)(ws + 1622016);       //  184320
    float* cst0 = (float*)(ws + 1806336);     //  262144
    float* cst1 = (float*)(ws + 2068480);     //  262144
    f16*   hst0 = (f16*)(ws + 2330624);       //  131072
    f16*   hst1 = (f16*)(ws + 2461696);       //  131072
    const size_t base = 2592768;

    // pick chunk length by available workspace: need base + TC*(128K + 512K + 128K)
    int TC = 64;
    if (ws_size >= base + (size_t)256 * 786432 + (1u << 20)) TC = 256;
    else if (ws_size >= base + (size_t)128 * 786432 + (1u << 20)) TC = 128;

    f16* h1c = (f16*)(ws + base);
    f16* xgc = (f16*)(ws + base + (size_t)TC * 131072);
    f16* h2c = (f16*)(ws + base + (size_t)TC * 131072 + (size_t)TC * 524288);

    hipFuncSetAttribute(reinterpret_cast<const void*>(rnn_chunk<0>),
                        hipFuncAttributeMaxDynamicSharedMemorySize, R_LDS_BYTES);
    hipFuncSetAttribute(reinterpret_cast<const void*>(rnn_chunk<1>),
                        hipFuncAttributeMaxDynamicSharedMemorySize, R_LDS_BYTES);

    build_t0p<<<90, 256, 0, stream>>>(emb, wih0, bih0, bhh0, T0p);
    pack_rw<<<128, 256, 0, stream>>>(whh0, Wp0);
    pack_rw<<<128, 256, 0, stream>>>(whh1, Wp1);
    pack_rw<<<128, 256, 0, stream>>>(wih1, Wxp);
    pack_fc<<<12, 256, 0, stream>>>(wfc, Wfcp);

    for (int t0 = 0; t0 < NS; t0 += TC) {
        rnn_chunk<0><<<16, 256, R_LDS_BYTES, stream>>>(Wp0, x, T0p, nullptr,
                                                       h1c, cst0, hst0, t0, TC);
        xg1_gemm<<<16 * 4 * (TC / 16), 256, 0, stream>>>(h1c, Wxp, bih1, bhh1, xgc);
        rnn_chunk<1><<<16, 256, R_LDS_BYTES, stream>>>(Wp1, nullptr, nullptr, xgc,
                                                       h2c, cst1, hst1, t0, TC);
        fc_out<<<16 * (TC / 4), 256, 0, stream>>>(h2c, Wfcp, bfc, out, t0);
    }
}